// Round 9
// baseline (258.603 us; speedup 1.0000x reference)
//
#include <hip/hip_runtime.h>
#include <math.h>

// PositionFeaturizer on MI355X — round 16:
//  * prep_all measured 40.1 us vs 16 us BW floor (VALU 9.6%, HBM 31% —
//    instruction-issue / latency bound). Fixes, all instr-per-byte:
//      - weight cast vectorized 8/thread (float4 x2 -> bf16x8), 288 blocks
//      - LN: 4 rows per wave, g/b loaded ONCE, x prefetched one row ahead
//      - edge records: 2 edges/thread (e, e+256), doubled chain ILP
//  * edge_csr: 16-deep serial fmaf dot -> 4 parallel 4-deep chains + tree
//    (critical path /4; kernel was 30% VALU latency-bound).
//  * gemm256 / gemm_mlp / launch structure unchanged from r15 (254.6 best).

typedef unsigned short u16;
typedef __attribute__((ext_vector_type(8))) short bf16x8;   // 8 bf16 in 4 VGPRs
typedef __attribute__((ext_vector_type(4))) float f32x4;
typedef __attribute__((ext_vector_type(2))) float f32x2;

constexpr int N_NODES = 16384;
constexpr int E_EDGES = 262144;
constexpr int D = 512;
constexpr int KIN = 576;    // 536 padded to 9*64

// workspace layout (bytes)
constexpr size_t OFF_ZATT = 0;                       // 16384*512*2  = 16,777,216
constexpr size_t OFF_ZCAT = 16777216;                // 16384*576*2  = 18,874,368
constexpr size_t OFF_WQK  = 35651584;                // 1024*512*2   = 1,048,576
constexpr size_t OFF_BQK  = 36700160;                // 1024*4       = 4,096
constexpr size_t OFF_WIN  = 36704256;                // 1024*576*2   = 1,179,648
constexpr size_t OFF_WOUT = 37883904;                // 512*1024*2   = 1,048,576
constexpr size_t OFF_QK   = 38932480;                // 16384*1024*1 = 16,777,216 (fp8)
constexpr size_t OFF_BKT  = 55775232;                // 16384*64*4 = 4,194,304
constexpr size_t OFF_HBF  = 59969536;                // 16384*1024*2 = 33,554,432
constexpr size_t OFF_REC  = 93523968;                // 262144*64 = 16,777,216
constexpr size_t OFF_CNTP = 110301184;               // 16384*64 = 1,048,576

static __device__ __forceinline__ u16 f2bf(float f) {
  union { float f; unsigned int u; } v; v.f = f;
  unsigned int u = v.u;
  u = u + 0x7FFFu + ((u >> 16) & 1u);   // RNE
  return (u16)(u >> 16);
}
// async global->LDS, 16 B per lane; LDS dest = wave-uniform base + lane*16
static __device__ __forceinline__ void gload16(const u16* g, u16* l) {
  __builtin_amdgcn_global_load_lds(
      (const __attribute__((address_space(1))) unsigned int*)g,
      (__attribute__((address_space(3))) unsigned int*)l, 16, 0, 0);
}

// ---------------------------------------------------------------- fused prep: edges + weights + dual LN
// blocks [0,512): edge records+CSR, 2 edges/thread
// blocks [512,800): weight casts, 8 elems/thread
// blocks [800,1824): dual LN, 4 rows/wave
__global__ __launch_bounds__(256) void prep_all(
    const int* __restrict__ row_index,
    const float* __restrict__ att_bias, const float* __restrict__ dist,
    const float* __restrict__ src_pos, const int* __restrict__ src_index,
    const int* __restrict__ org_to_src,
    int* __restrict__ cntp, int* __restrict__ bucket, float* __restrict__ rec,
    const float* __restrict__ Wq, const float* __restrict__ Wk,
    const float* __restrict__ bq, const float* __restrict__ bk,
    const float* __restrict__ W_in, const float* __restrict__ W_out,
    u16* __restrict__ wqk, float* __restrict__ bqk,
    u16* __restrict__ win, u16* __restrict__ wout,
    const float* __restrict__ x,
    const float* __restrict__ g1, const float* __restrict__ b1,
    const float* __restrict__ g2, const float* __restrict__ b2,
    u16* __restrict__ zatt, u16* __restrict__ zcat)
{
  if (blockIdx.x < 512) {
    // ------- edge records + bucket CSR: 2 edges/thread -------
    const int e0 = blockIdx.x * 512 + threadIdx.x;
#pragma unroll
    for (int k = 0; k < 2; ++k) {
      const int gid = e0 + k * 256;
      const int r = row_index[gid];
      const int s = src_index[gid];
      const float dv = dist[gid];
      float4 q0, q1, q2, q3;
      q0.x = att_bias[gid];
      q0.y = att_bias[(size_t)1 * E_EDGES + gid];
      q0.z = att_bias[(size_t)2 * E_EDGES + gid];
      q0.w = att_bias[(size_t)3 * E_EDGES + gid];
      q1.x = att_bias[(size_t)4 * E_EDGES + gid];
      q1.y = att_bias[(size_t)5 * E_EDGES + gid];
      q1.z = att_bias[(size_t)6 * E_EDGES + gid];
      q1.w = att_bias[(size_t)7 * E_EDGES + gid];
      q2.x = (dv == 0.f) ? 0.f : 1.f / dv;   // matches ref: inv = 1/dist, then mul
      q2.y = src_pos[(size_t)s * 3 + 0];
      q2.z = src_pos[(size_t)s * 3 + 1];
      q2.w = src_pos[(size_t)s * 3 + 2];
      q3.x = __int_as_float(org_to_src[s]);
      q3.y = 0.f; q3.z = 0.f; q3.w = 0.f;
      float4* rg = (float4*)(rec + (size_t)gid * 16);
      rg[0] = q0; rg[1] = q1; rg[2] = q2; rg[3] = q3;
      const int p = atomicAdd(&cntp[r * 16], 1);   // 1 counter per 64-B line
      if (p < 64) bucket[(size_t)r * 64 + p] = gid;
    }
    return;
  }
  if (blockIdx.x < 800) {
    // ------- weight casts: 8 elems/thread (all boundaries %8==0) -------
    const int wgid = (blockIdx.x - 512) * 256 + threadIdx.x;
    const int g8 = wgid * 8;
    if (g8 < 512 * 1024) {
      // wqk: Wq for g8<262144, Wk after (262144%8==0 -> no mixed vector)
      const float* src = (g8 < 512 * 512) ? (Wq + g8) : (Wk + g8 - 512 * 512);
      const float4 a = *(const float4*)(src);
      const float4 b = *(const float4*)(src + 4);
      bf16x8 o;
      o[0] = (short)f2bf(a.x); o[1] = (short)f2bf(a.y);
      o[2] = (short)f2bf(a.z); o[3] = (short)f2bf(a.w);
      o[4] = (short)f2bf(b.x); o[5] = (short)f2bf(b.y);
      o[6] = (short)f2bf(b.z); o[7] = (short)f2bf(b.w);
      *(bf16x8*)(wqk + g8) = o;
      const float4 c = *(const float4*)(W_out + g8);
      const float4 d = *(const float4*)(W_out + g8 + 4);
      bf16x8 p;
      p[0] = (short)f2bf(c.x); p[1] = (short)f2bf(c.y);
      p[2] = (short)f2bf(c.z); p[3] = (short)f2bf(c.w);
      p[4] = (short)f2bf(d.x); p[5] = (short)f2bf(d.y);
      p[6] = (short)f2bf(d.z); p[7] = (short)f2bf(d.w);
      *(bf16x8*)(wout + g8) = p;
    }
    if (g8 < 1024 * KIN) {
      // win: row r, cols c0..c0+7; 536%8==0 -> vector fully in-range or all-pad
      const int r = g8 / KIN, c0 = g8 - r * KIN;
      bf16x8 o;
      if (c0 < 536) {
        const float* src = W_in + (size_t)r * 536 + c0;
        const float4 a = *(const float4*)(src);
        const float4 b = *(const float4*)(src + 4);
        o[0] = (short)f2bf(a.x); o[1] = (short)f2bf(a.y);
        o[2] = (short)f2bf(a.z); o[3] = (short)f2bf(a.w);
        o[4] = (short)f2bf(b.x); o[5] = (short)f2bf(b.y);
        o[6] = (short)f2bf(b.z); o[7] = (short)f2bf(b.w);
      } else {
        o = (bf16x8)(short)0;
      }
      *(bf16x8*)(win + g8) = o;
    }
    if (wgid < 1024) bqk[wgid] = wgid < 512 ? bq[wgid] : bk[wgid - 512];
    return;
  }
  // ------- dual LN: 4 rows per wave, g/b loaded once, x prefetched -------
  const int wv = threadIdx.x >> 6;
  const int l = threadIdx.x & 63;
  const int row0 = ((blockIdx.x - 800) * 4 + wv) * 4;
  const int c0 = l * 8;
  const float4 ga0 = *(const float4*)(g1 + c0), ga1 = *(const float4*)(g1 + c0 + 4);
  const float4 ba0 = *(const float4*)(b1 + c0), ba1 = *(const float4*)(b1 + c0 + 4);
  const float4 gm0 = *(const float4*)(g2 + c0), gm1 = *(const float4*)(g2 + c0 + 4);
  const float4 bm0 = *(const float4*)(b2 + c0), bm1 = *(const float4*)(b2 + c0 + 4);
  const float ga[8] = { ga0.x, ga0.y, ga0.z, ga0.w, ga1.x, ga1.y, ga1.z, ga1.w };
  const float ba[8] = { ba0.x, ba0.y, ba0.z, ba0.w, ba1.x, ba1.y, ba1.z, ba1.w };
  const float gm[8] = { gm0.x, gm0.y, gm0.z, gm0.w, gm1.x, gm1.y, gm1.z, gm1.w };
  const float bm[8] = { bm0.x, bm0.y, bm0.z, bm0.w, bm1.x, bm1.y, bm1.z, bm1.w };
  float4 xv0 = *(const float4*)(x + (size_t)row0 * D + c0);
  float4 xv1 = *(const float4*)(x + (size_t)row0 * D + c0 + 4);
#pragma unroll
  for (int rr = 0; rr < 4; ++rr) {
    const int row = row0 + rr;
    const float4 v0 = xv0, v1 = xv1;
    if (rr < 3) {     // prefetch next row while reducing this one
      xv0 = *(const float4*)(x + (size_t)(row + 1) * D + c0);
      xv1 = *(const float4*)(x + (size_t)(row + 1) * D + c0 + 4);
    }
    float s  = v0.x + v0.y + v0.z + v0.w + v1.x + v1.y + v1.z + v1.w;
    float s2 = v0.x * v0.x + v0.y * v0.y + v0.z * v0.z + v0.w * v0.w
             + v1.x * v1.x + v1.y * v1.y + v1.z * v1.z + v1.w * v1.w;
#pragma unroll
    for (int m = 1; m < 64; m <<= 1) {
      s  += __shfl_xor(s, m, 64);
      s2 += __shfl_xor(s2, m, 64);
    }
    const float mu = s * (1.f / D);
    const float var = s2 * (1.f / D) - mu * mu;
    const float rs = rsqrtf(var + 1e-5f);
    const float n[8] = { (v0.x - mu) * rs, (v0.y - mu) * rs, (v0.z - mu) * rs, (v0.w - mu) * rs,
                         (v1.x - mu) * rs, (v1.y - mu) * rs, (v1.z - mu) * rs, (v1.w - mu) * rs };
    bf16x8 za, zc;
#pragma unroll
    for (int i = 0; i < 8; ++i) {
      za[i] = (short)f2bf(n[i] * ga[i] + ba[i]);
      zc[i] = (short)f2bf(n[i] * gm[i] + bm[i]);
    }
    *(bf16x8*)(zatt + (size_t)row * D + c0) = za;
    *(bf16x8*)(zcat + (size_t)row * KIN + c0) = zc;
    if (l < 32) ((unsigned int*)(zcat + (size_t)row * KIN + D))[l] = 0;  // feat+pad zero
  }
}

// ---------------------------------------------------------------- 256^2 8-wave deep-pipelined NT GEMM
#define MM_BLK(AF, BF, NB) do {                                               \
  __builtin_amdgcn_s_setprio(1);                                              \
  _Pragma("unroll")                                                           \
  for (int mi = 0; mi < 8; ++mi) {                                            \
    acc[mi][NB]     = __builtin_amdgcn_mfma_f32_16x16x32_bf16(AF[mi], BF[0], acc[mi][NB], 0, 0, 0);     \
    acc[mi][NB + 1] = __builtin_amdgcn_mfma_f32_16x16x32_bf16(AF[mi], BF[1], acc[mi][NB + 1], 0, 0, 0); \
  }                                                                           \
  __builtin_amdgcn_s_setprio(0);                                              \
} while (0)

template <int EPI>
__global__ __launch_bounds__(512, 2) void gemm256(
    const u16* __restrict__ A, const u16* __restrict__ B,
    const float* __restrict__ bias,
    void* __restrict__ Cout, int M, int Nn, int K)
{
  extern __shared__ __align__(16) u16 lds[];   // 65536 u16 = 128 KiB
  const int tid = threadIdx.x;
  const int lane = tid & 63;
  const int wave = tid >> 6;          // 0..7
  const int wave_m = wave >> 2;
  const int wave_n = wave & 3;
  const int m0 = blockIdx.x * 256;
  const int n0 = blockIdx.y * 256;
  const int fr = lane & 15;
  const int fq = lane >> 4;
  const int NT = K >> 6;
  const int sw = (fq ^ ((fr >> 1) & 3)) * 8;

  f32x4 acc[8][4];
#pragma unroll
  for (int i = 0; i < 8; ++i)
#pragma unroll
    for (int j = 0; j < 4; ++j) acc[i][j] = 0.f;

  auto stageA = [&](int slot, int ktile, int kh) {
    u16* base = lds + slot * 8192;
    const int kb = ktile * 64 + kh * 32;
#pragma unroll
    for (int r = 0; r < 2; ++r) {
      const int g = r * 512 + tid;
      const int row = g >> 2;
      const int gs = (g & 3) ^ ((row >> 1) & 3);
      gload16(A + (size_t)(m0 + row) * K + kb + gs * 8,
              base + (r * 512 + wave * 64) * 8);
    }
  };
  auto stageB = [&](int slot, int ktile, int kh) {
    u16* base = lds + 32768 + slot * 8192;
    const int kb = ktile * 64 + kh * 32;
#pragma unroll
    for (int r = 0; r < 2; ++r) {
      const int g = r * 512 + tid;
      const int row = g >> 2;
      const int gs = (g & 3) ^ ((row >> 1) & 3);
      gload16(B + (size_t)(n0 + row) * K + kb + gs * 8,
              base + (r * 512 + wave * 64) * 8);
    }
  };
  auto ldA = [&](bf16x8 (&af)[8], int slot) {
    const u16* p = lds + slot * 8192 + (wave_m * 128 + fr) * 32 + sw;
#pragma unroll
    for (int mi = 0; mi < 8; ++mi)
      af[mi] = *(const bf16x8*)(p + mi * 16 * 32);
  };
  auto ldB = [&](bf16x8 (&bf)[2], int slot, int nh) {
    const u16* p = lds + 32768 + slot * 8192 + (wave_n * 64 + nh * 32 + fr) * 32 + sw;
    bf[0] = *(const bf16x8*)(p);
    bf[1] = *(const bf16x8*)(p + 16 * 32);
  };

  stageA(0, 0, 0); stageB(0, 0, 0);
  stageA(1, 0, 1); stageB(1, 0, 1);
  stageA(2, 1, 0); stageB(2, 1, 0);
  stageA(3, 1, 1);
  asm volatile("s_waitcnt vmcnt(10)" ::: "memory");
  __builtin_amdgcn_s_barrier();
  asm volatile("" ::: "memory");

  bf16x8 af[8], bf0[2], bf1[2];
  for (int t = 0; t < NT; ++t) {
    const int sa0 = (2 * t) & 3,  sa1 = (2 * t + 1) & 3;
    const int sb1n = (2 * t + 3) & 3;
    const int t1 = (t + 1 >= NT) ? t + 1 - NT : t + 1;
    const int t2 = (t + 2 >= NT) ? t + 2 - NT : t + 2;

    ldA(af, sa0); ldB(bf0, sa0, 0);
    stageB(sb1n, t1, 1);
    __builtin_amdgcn_s_barrier();
    asm volatile("" ::: "memory");
    MM_BLK(af, bf0, 0);
    __builtin_amdgcn_s_barrier();
    asm volatile("" ::: "memory");
    ldB(bf1, sa0, 1);
    stageA(sa0, t2, 0);
    __builtin_amdgcn_s_barrier();
    asm volatile("" ::: "memory");
    MM_BLK(af, bf1, 2);
    asm volatile("s_waitcnt vmcnt(10)" ::: "memory");
    __builtin_amdgcn_s_barrier();
    asm volatile("" ::: "memory");
    ldA(af, sa1); ldB(bf0, sa1, 0);
    stageB(sa0, t2, 0);
    __builtin_amdgcn_s_barrier();
    asm volatile("" ::: "memory");
    MM_BLK(af, bf0, 0);
    __builtin_amdgcn_s_barrier();
    asm volatile("" ::: "memory");
    ldB(bf1, sa1, 1);
    stageA(sa1, t2, 1);
    __builtin_amdgcn_s_barrier();
    asm volatile("" ::: "memory");
    MM_BLK(af, bf1, 2);
    asm volatile("s_waitcnt vmcnt(10)" ::: "memory");
    __builtin_amdgcn_s_barrier();
    asm volatile("" ::: "memory");
  }
  asm volatile("s_waitcnt vmcnt(0)" ::: "memory");

#pragma unroll
  for (int mi = 0; mi < 8; ++mi) {
#pragma unroll
    for (int nj = 0; nj < 4; ++nj) {
      const int col = n0 + wave_n * 64 + nj * 16 + fr;
      const float bv = bias[col];
#pragma unroll
      for (int rr = 0; rr < 4; ++rr) {
        const int row = m0 + wave_m * 128 + mi * 16 + fq * 4 + rr;
        float v = acc[mi][nj][rr] + bv;
        if (EPI == 1) {
          const float nu = -1.5957691216057308f * (v + 0.044715f * v * v * v);
          const float sg = __builtin_amdgcn_rcpf(1.f + __expf(nu));
          ((u16*)Cout)[(size_t)row * Nn + col] = f2bf(v * sg);
        } else {
          const int pk = __builtin_amdgcn_cvt_pk_fp8_f32(v, v, 0, false);
          ((unsigned char*)Cout)[(size_t)row * Nn + col] = (unsigned char)(pk & 0xFF);
        }
      }
    }
  }
}

// ---------------------------------------------------------------- gemm3: deep-pipelined BM=256 x BN=128 (grid 64x4 = 1/CU)
__global__ __launch_bounds__(512, 2) void gemm_mlp(
    const u16* __restrict__ A, const u16* __restrict__ B,
    const float* __restrict__ bias, const float* __restrict__ resid,
    float* __restrict__ Cout, int M, int Nn, int K)
{
  extern __shared__ __align__(16) u16 lds[];   // A: 4 x 8192 u16; B: 4 x 4096 u16 at +32768
  const int tid = threadIdx.x;
  const int lane = tid & 63;
  const int wave = tid >> 6;
  const int wave_m = wave >> 2;       // 0..1
  const int wave_n = wave & 3;        // 0..3
  const int m0 = blockIdx.x * 256;
  const int n0 = blockIdx.y * 128;
  const int fr = lane & 15;
  const int fq = lane >> 4;
  const int NT = K >> 6;              // 16
  const int sw = (fq ^ ((fr >> 1) & 3)) * 8;

  f32x4 acc[8][2];
#pragma unroll
  for (int i = 0; i < 8; ++i) { acc[i][0] = 0.f; acc[i][1] = 0.f; }

  auto stageA = [&](int slot, int ktile, int kh) {     // [256][32], 2 gloads
    u16* base = lds + slot * 8192;
    const int kb = ktile * 64 + kh * 32;
#pragma unroll
    for (int r = 0; r < 2; ++r) {
      const int g = r * 512 + tid;
      const int row = g >> 2;
      const int gs = (g & 3) ^ ((row >> 1) & 3);
      gload16(A + (size_t)(m0 + row) * K + kb + gs * 8,
              base + (r * 512 + wave * 64) * 8);
    }
  };
  auto stageB = [&](int slot, int ktile, int kh) {     // [128][32], 1 gload
    u16* base = lds + 32768 + slot * 4096;
    const int kb = ktile * 64 + kh * 32;
    const int row = tid >> 2;
    const int gs = (tid & 3) ^ ((row >> 1) & 3);
    gload16(B + (size_t)(n0 + row) * K + kb + gs * 8,
            base + (wave * 64 + lane) * 8);
  };
  auto ldA = [&](bf16x8 (&af)[8], int slot) {
    const u16* p = lds + slot * 8192 + (wave_m * 128 + fr) * 32 + sw;
#pragma unroll
    for (int mi = 0; mi < 8; ++mi)
      af[mi] = *(const bf16x8*)(p + mi * 16 * 32);
  };
  auto ldB2 = [&](bf16x8 (&bf)[2], int slot) {
    const u16* p = lds + 32768 + slot * 4096 + (wave_n * 32 + fr) * 32 + sw;
    bf[0] = *(const bf16x8*)(p);
    bf[1] = *(const bf16x8*)(p + 16 * 32);
  };

  stageA(0, 0, 0); stageB(0, 0, 0);
  stageA(1, 0, 1); stageB(1, 0, 1);
  stageA(2, 1, 0); stageB(2, 1, 0);
  asm volatile("s_waitcnt vmcnt(6)" ::: "memory");
  __builtin_amdgcn_s_barrier();
  asm volatile("" ::: "memory");

  bf16x8 af[8], bf[2];
  for (int t = 0; t < NT; ++t) {
    const int sa0 = (2 * t) & 3, sa1 = (2 * t + 1) & 3;
    const int sn  = (2 * t + 3) & 3;
    const int t1 = (t + 1 >= NT) ? t + 1 - NT : t + 1;
    const int t2 = (t + 2 >= NT) ? t + 2 - NT : t + 2;

    ldA(af, sa0); ldB2(bf, sa0);
    stageA(sn, t1, 1); stageB(sn, t1, 1);
    __builtin_amdgcn_s_barrier();
    asm volatile("" ::: "memory");
    MM_BLK(af, bf, 0);
    asm volatile("s_waitcnt vmcnt(6)" ::: "memory");
    __builtin_amdgcn_s_barrier();
    asm volatile("" ::: "memory");
    ldA(af, sa1); ldB2(bf, sa1);
    stageA(sa0, t2, 0); stageB(sa0, t2, 0);
    __builtin_amdgcn_s_barrier();
    asm volatile("" ::: "memory");
    MM_BLK(af, bf, 0);
    asm volatile("s_waitcnt vmcnt(6)" ::: "memory");
    __builtin_amdgcn_s_barrier();
    asm volatile("" ::: "memory");
  }
  asm volatile("s_waitcnt vmcnt(0)" ::: "memory");

#pragma unroll
  for (int mi = 0; mi < 8; ++mi) {
#pragma unroll
    for (int nj = 0; nj < 2; ++nj) {
      const int col = n0 + wave_n * 32 + nj * 16 + fr;
      const float bv = bias[col];
#pragma unroll
      for (int rr = 0; rr < 4; ++rr) {
        const int row = m0 + wave_m * 128 + mi * 16 + fq * 4 + rr;
        Cout[(size_t)row * Nn + col] = acc[mi][nj][rr] + bv + resid[(size_t)row * Nn + col];
      }
    }
  }
}

// ---------------------------------------------------------------- edge pass (bucket CSR + edge records)
// 4-stage pipeline: bucket@i+4, rec@i+3, kv@i+2, compute@i.
// Dot product: 4 parallel 4-deep fmaf chains + tree combine.
__global__ __launch_bounds__(256) void edge_csr(
    const unsigned char* __restrict__ qk8, const float* __restrict__ rec,
    const int* __restrict__ cntp, const int* __restrict__ bucket,
    const float* __restrict__ pos, u16* __restrict__ zcat)
{
  const int lane = threadIdx.x & 63;
  const int wave = threadIdx.x >> 6;
  const int row = blockIdx.x * 4 + wave;
  const int half = lane >> 5;
  const int sub = lane & 31;
  const int h = sub >> 2, j = sub & 3;
  const int deg = min(cntp[row * 16], 64);
  const int base = row * 64;

  const uint4 qv = *(const uint4*)(qk8 + (size_t)row * 1024 + sub * 16);
  float qf[16];
  {
    const unsigned int* qu = (const unsigned int*)&qv;
#pragma unroll
    for (int i = 0; i < 4; ++i) {
      const f32x2 lo = __builtin_amdgcn_cvt_pk_f32_fp8(qu[i], false);
      const f32x2 hi = __builtin_amdgcn_cvt_pk_f32_fp8(qu[i], true);
      qf[i * 4 + 0] = lo.x; qf[i * 4 + 1] = lo.y;
      qf[i * 4 + 2] = hi.x; qf[i * 4 + 3] = hi.y;
    }
  }

  float accA = 0.f, accB = 0.f;
  const int npair = (deg + 1) >> 1;

  bool ok0 = half < deg;
  int e0 = ok0 ? bucket[base + half] : 0;
  const float* r0 = rec + (size_t)e0 * 16;
  float bias0 = r0[h], invd0 = r0[8];
  float spA0 = (j >= 2) ? r0[7 + j] : 0.f;
  float spB0 = (j == 1) ? r0[11] : 0.f;
  uint4 kv0 = *(const uint4*)(qk8 + (size_t)__float_as_int(r0[12]) * 1024 + 512 + sub * 16);

  bool ok1 = 2 + half < deg;
  int e1 = ok1 ? bucket[base + 2 + half] : 0;
  const float* r1 = rec + (size_t)e1 * 16;
  float bias1 = r1[h], invd1 = r1[8];
  float spA1 = (j >= 2) ? r1[7 + j] : 0.f;
  float spB1 = (j == 1) ? r1[11] : 0.f;
  uint4 kv1 = *(const uint4*)(qk8 + (size_t)__float_as_int(r1[12]) * 1024 + 512 + sub * 16);

  bool ok2 = 4 + half < deg;
  int e2 = ok2 ? bucket[base + 4 + half] : 0;
  const float* r2p = rec + (size_t)e2 * 16;
  float bias2 = r2p[h], invd2 = r2p[8];
  float spA2 = (j >= 2) ? r2p[7 + j] : 0.f;
  float spB2 = (j == 1) ? r2p[11] : 0.f;
  int kr2 = __float_as_int(r2p[12]);

  bool ok3 = 6 + half < deg;
  int e3 = ok3 ? bucket[base + 6 + half] : 0;

  for (int i = 0; i < npair; ++i) {
    const uint4 kv2 = *(const uint4*)(qk8 + (size_t)kr2 * 1024 + 512 + sub * 16);
    const float* r3 = rec + (size_t)e3 * 16;
    const float bias3 = r3[h], invd3 = r3[8];
    const float spA3 = (j >= 2) ? r3[7 + j] : 0.f;
    const float spB3 = (j == 1) ? r3[11] : 0.f;
    const int kr3 = __float_as_int(r3[12]);
    const bool ok4 = 2 * (i + 4) + half < deg;
    const int e4 = ok4 ? bucket[base + 2 * (i + 4) + half] : 0;

    float p;
    {
      const unsigned int* ku = (const unsigned int*)&kv0;
      const f32x2 a0 = __builtin_amdgcn_cvt_pk_f32_fp8(ku[0], false);
      const f32x2 a1 = __builtin_amdgcn_cvt_pk_f32_fp8(ku[0], true);
      const f32x2 b0 = __builtin_amdgcn_cvt_pk_f32_fp8(ku[1], false);
      const f32x2 b1 = __builtin_amdgcn_cvt_pk_f32_fp8(ku[1], true);
      const f32x2 c0 = __builtin_amdgcn_cvt_pk_f32_fp8(ku[2], false);
      const f32x2 c1 = __builtin_amdgcn_cvt_pk_f32_fp8(ku[2], true);
      const f32x2 d0 = __builtin_amdgcn_cvt_pk_f32_fp8(ku[3], false);
      const f32x2 d1 = __builtin_amdgcn_cvt_pk_f32_fp8(ku[3], true);
      // 4 parallel 4-deep chains (critical path /4 vs serial 16)
      float pA = qf[0] * a0.x;
      float pB = qf[4] * b0.x;
      float pC = qf[8] * c0.x;
      float pD = qf[12] * d0.x;
      pA = fmaf(qf[1],  a0.y, pA);  pB = fmaf(qf[5],  b0.y, pB);
      pC = fmaf(qf[9],  c0.y, pC);  pD = fmaf(qf[13], d0.y, pD);
      pA = fmaf(qf[2],  a1.x, pA);  pB = fmaf(qf[6],  b1.x, pB);
      pC = fmaf(qf[10], c1.x, pC);  pD = fmaf(qf[14], d1.x, pD);
      pA = fmaf(qf[3],  a1.y, pA);  pB = fmaf(qf[7],  b1.y, pB);
      pC = fmaf(qf[11], c1.y, pC);  pD = fmaf(qf[15], d1.y, pD);
      p = (pA + pB) + (pC + pD);
    }
    p += __shfl_xor(p, 1, 64);
    p += __shfl_xor(p, 2, 64);
    float pe = __expf(p * 0.125f + bias0);
    pe = ok0 ? pe : 0.f;
    const float w = pe * invd0;
    accA += (j == 0) ? pe : (j == 1) ? w : w * spA0;
    accB += w * spB0;

    ok0 = ok1; bias0 = bias1; invd0 = invd1; spA0 = spA1; spB0 = spB1; kv0 = kv1;
    ok1 = ok2; bias1 = bias2; invd1 = invd2; spA1 = spA2; spB1 = spB2; kv1 = kv2;
    ok2 = ok3; bias2 = bias3; invd2 = invd3; spA2 = spA3; spB2 = spB3; kr2 = kr3;
    ok3 = ok4; e3 = e4;
  }

  accA += __shfl_xor(accA, 32, 64);
  accB += __shfl_xor(accB, 32, 64);
  const int hb = h << 2;
  const float den  = __shfl(accA, hb + 0, 64);
  const float wsum = __shfl(accA, hb + 1, 64);
  const float wsp01 = __shfl(accA, hb + 2 + (j & 1), 64);
  const float wsp2  = __shfl(accB, hb + 1, 64);
  const float invd = (den != 0.f) ? 1.f / den : 0.f;
  const float rsum = wsum * invd;
  if (half == 0 && j < 3) {
    const float wspj = (j < 2) ? wsp01 : wsp2;
    zcat[(size_t)row * KIN + D + h * 3 + j] = f2bf(wspj * invd - rsum * pos[row * 3 + j]);
  }
}

// ---------------------------------------------------------------- launch
extern "C" void kernel_launch(void* const* d_in, const int* in_sizes, int n_in,
                              void* d_out, int out_size, void* d_ws, size_t ws_size,
                              hipStream_t stream)
{
  const float* x        = (const float*)d_in[0];
  const float* Wq       = (const float*)d_in[1];
  const float* bq       = (const float*)d_in[2];
  const float* Wk       = (const float*)d_in[3];
  const float* bk       = (const float*)d_in[4];
  const float* g_att    = (const float*)d_in[5];
  const float* b_att    = (const float*)d_in[6];
  const float* g_mlp    = (const float*)d_in[7];
  const float* b_mlp    = (const float*)d_in[8];
  const float* W_in     = (const float*)d_in[9];
  const float* b_in     = (const float*)d_in[10];
  const float* W_out    = (const float*)d_in[11];
  const float* b_out    = (const float*)d_in[12];
  const float* att_bias = (const float*)d_in[13];
  const float* dist     = (const float*)d_in[14];
  const float* pos      = (const float*)d_in[15];
  const float* src_pos  = (const float*)d_in[16];
  const int* row_index  = (const int*)d_in[17];
  const int* src_index  = (const int*)d_in[18];
  const int* org_to_src = (const int*)d_in[19];

  char* ws = (char*)d_ws;
  u16*   zatt = (u16*)(ws + OFF_ZATT);
  u16*   zcat = (u16*)(ws + OFF_ZCAT);
  u16*   wqk  = (u16*)(ws + OFF_WQK);
  float* bqk  = (float*)(ws + OFF_BQK);
  u16*   win  = (u16*)(ws + OFF_WIN);
  u16*   wout = (u16*)(ws + OFF_WOUT);
  unsigned char* qk8 = (unsigned char*)(ws + OFF_QK);
  int*   bkt  = (int*)(ws + OFF_BKT);
  u16*   hbf  = (u16*)(ws + OFF_HBF);
  float* rec  = (float*)(ws + OFF_REC);
  int*   cntp = (int*)(ws + OFF_CNTP);

  static bool s_attr = false;
  if (!s_attr) {
    hipFuncSetAttribute(reinterpret_cast<const void*>(&gemm256<4>),
                        hipFuncAttributeMaxDynamicSharedMemorySize, 131072);
    hipFuncSetAttribute(reinterpret_cast<const void*>(&gemm256<1>),
                        hipFuncAttributeMaxDynamicSharedMemorySize, 131072);
    hipFuncSetAttribute(reinterpret_cast<const void*>(&gemm_mlp),
                        hipFuncAttributeMaxDynamicSharedMemorySize, 98304);
    s_attr = true;
  }

  hipMemsetAsync(ws + OFF_CNTP, 0, 16384 * 64, stream);

  prep_all<<<512 + 288 + 1024, 256, 0, stream>>>(
      row_index, att_bias, dist, src_pos, src_index, org_to_src, cntp, bkt, rec,
      Wq, Wk, bq, bk, W_in, W_out, wqk, bqk, win, wout,
      x, g_att, b_att, g_mlp, b_mlp, zatt, zcat);
  gemm256<4><<<dim3(64, 4), 512, 131072, stream>>>(zatt, wqk, bqk, qk8, N_NODES, 1024, 512);
  edge_csr<<<N_NODES / 4, 256, 0, stream>>>(qk8, rec, cntp, bkt, pos, zcat);
  gemm256<1><<<dim3(64, 4), 512, 131072, stream>>>(zcat, win, b_in, hbf, N_NODES, 1024, KIN);
  gemm_mlp<<<dim3(64, 4), 512, 98304, stream>>>(hbf, wout, b_out, x, (float*)d_out, N_NODES, 512, 1024);
}

// Round 10
// 252.113 us; speedup vs baseline: 1.0257x; 1.0257x over previous
//
#include <hip/hip_runtime.h>
#include <math.h>

// PositionFeaturizer on MI355X — round 17:
//  * r16 post-mortem: prep_all is TLP-bound (occ 63->47%, 40.1->42.7 us when
//    block count dropped 3904->1824). REVERT to high-TLP shapes: edge 1
//    edge/thread (1024 blocks), LN wave-per-row (4096 blocks). KEEP r16's
//    vectorized weight cast (288 blocks; fewer instrs, same bytes) and
//    edge_csr's 4-parallel-chain dot.
//  * ERRATA r14: REP diagnostic zeroed acc per rep -> reps' MFMAs were DCE'd
//    (rule #17); "gemm body ~6us" measured staging only. gemm structure
//    conclusions re-based on r15's measured net win only.
//  * Everything else unchanged from r15/r16 (best = r15's 254.6).

typedef unsigned short u16;
typedef __attribute__((ext_vector_type(8))) short bf16x8;   // 8 bf16 in 4 VGPRs
typedef __attribute__((ext_vector_type(4))) float f32x4;
typedef __attribute__((ext_vector_type(2))) float f32x2;

constexpr int N_NODES = 16384;
constexpr int E_EDGES = 262144;
constexpr int D = 512;
constexpr int KIN = 576;    // 536 padded to 9*64

// workspace layout (bytes)
constexpr size_t OFF_ZATT = 0;                       // 16384*512*2  = 16,777,216
constexpr size_t OFF_ZCAT = 16777216;                // 16384*576*2  = 18,874,368
constexpr size_t OFF_WQK  = 35651584;                // 1024*512*2   = 1,048,576
constexpr size_t OFF_BQK  = 36700160;                // 1024*4       = 4,096
constexpr size_t OFF_WIN  = 36704256;                // 1024*576*2   = 1,179,648
constexpr size_t OFF_WOUT = 37883904;                // 512*1024*2   = 1,048,576
constexpr size_t OFF_QK   = 38932480;                // 16384*1024*1 = 16,777,216 (fp8)
constexpr size_t OFF_BKT  = 55775232;                // 16384*64*4 = 4,194,304
constexpr size_t OFF_HBF  = 59969536;                // 16384*1024*2 = 33,554,432
constexpr size_t OFF_REC  = 93523968;                // 262144*64 = 16,777,216
constexpr size_t OFF_CNTP = 110301184;               // 16384*64 = 1,048,576

static __device__ __forceinline__ u16 f2bf(float f) {
  union { float f; unsigned int u; } v; v.f = f;
  unsigned int u = v.u;
  u = u + 0x7FFFu + ((u >> 16) & 1u);   // RNE
  return (u16)(u >> 16);
}
// async global->LDS, 16 B per lane; LDS dest = wave-uniform base + lane*16
static __device__ __forceinline__ void gload16(const u16* g, u16* l) {
  __builtin_amdgcn_global_load_lds(
      (const __attribute__((address_space(1))) unsigned int*)g,
      (__attribute__((address_space(3))) unsigned int*)l, 16, 0, 0);
}

// ---------------------------------------------------------------- fused prep: edges + weights + dual LN
// blocks [0,1024): edge records+CSR, 1 edge/thread (max TLP)
// blocks [1024,1312): weight casts, 8 elems/thread (vectorized)
// blocks [1312,5408): dual LN, wave-per-row (4 rows/block)
__global__ __launch_bounds__(256) void prep_all(
    const int* __restrict__ row_index,
    const float* __restrict__ att_bias, const float* __restrict__ dist,
    const float* __restrict__ src_pos, const int* __restrict__ src_index,
    const int* __restrict__ org_to_src,
    int* __restrict__ cntp, int* __restrict__ bucket, float* __restrict__ rec,
    const float* __restrict__ Wq, const float* __restrict__ Wk,
    const float* __restrict__ bq, const float* __restrict__ bk,
    const float* __restrict__ W_in, const float* __restrict__ W_out,
    u16* __restrict__ wqk, float* __restrict__ bqk,
    u16* __restrict__ win, u16* __restrict__ wout,
    const float* __restrict__ x,
    const float* __restrict__ g1, const float* __restrict__ b1,
    const float* __restrict__ g2, const float* __restrict__ b2,
    u16* __restrict__ zatt, u16* __restrict__ zcat)
{
  if (blockIdx.x < 1024) {
    // ------- edge records + bucket CSR: 1 edge/thread -------
    const int gid = blockIdx.x * 256 + threadIdx.x;   // < E_EDGES
    const int r = row_index[gid];
    const int s = src_index[gid];
    const float dv = dist[gid];
    float4 q0, q1, q2, q3;
    q0.x = att_bias[gid];
    q0.y = att_bias[(size_t)1 * E_EDGES + gid];
    q0.z = att_bias[(size_t)2 * E_EDGES + gid];
    q0.w = att_bias[(size_t)3 * E_EDGES + gid];
    q1.x = att_bias[(size_t)4 * E_EDGES + gid];
    q1.y = att_bias[(size_t)5 * E_EDGES + gid];
    q1.z = att_bias[(size_t)6 * E_EDGES + gid];
    q1.w = att_bias[(size_t)7 * E_EDGES + gid];
    q2.x = (dv == 0.f) ? 0.f : 1.f / dv;   // matches ref: inv = 1/dist, then mul
    q2.y = src_pos[(size_t)s * 3 + 0];
    q2.z = src_pos[(size_t)s * 3 + 1];
    q2.w = src_pos[(size_t)s * 3 + 2];
    q3.x = __int_as_float(org_to_src[s]);
    q3.y = 0.f; q3.z = 0.f; q3.w = 0.f;
    float4* rg = (float4*)(rec + (size_t)gid * 16);
    rg[0] = q0; rg[1] = q1; rg[2] = q2; rg[3] = q3;
    const int p = atomicAdd(&cntp[r * 16], 1);   // 1 counter per 64-B line
    if (p < 64) bucket[(size_t)r * 64 + p] = gid;
    return;
  }
  if (blockIdx.x < 1312) {
    // ------- weight casts: 8 elems/thread (all boundaries %8==0) -------
    const int wgid = (blockIdx.x - 1024) * 256 + threadIdx.x;
    const int g8 = wgid * 8;
    if (g8 < 512 * 1024) {
      const float* src = (g8 < 512 * 512) ? (Wq + g8) : (Wk + g8 - 512 * 512);
      const float4 a = *(const float4*)(src);
      const float4 b = *(const float4*)(src + 4);
      bf16x8 o;
      o[0] = (short)f2bf(a.x); o[1] = (short)f2bf(a.y);
      o[2] = (short)f2bf(a.z); o[3] = (short)f2bf(a.w);
      o[4] = (short)f2bf(b.x); o[5] = (short)f2bf(b.y);
      o[6] = (short)f2bf(b.z); o[7] = (short)f2bf(b.w);
      *(bf16x8*)(wqk + g8) = o;
      const float4 c = *(const float4*)(W_out + g8);
      const float4 d = *(const float4*)(W_out + g8 + 4);
      bf16x8 p;
      p[0] = (short)f2bf(c.x); p[1] = (short)f2bf(c.y);
      p[2] = (short)f2bf(c.z); p[3] = (short)f2bf(c.w);
      p[4] = (short)f2bf(d.x); p[5] = (short)f2bf(d.y);
      p[6] = (short)f2bf(d.z); p[7] = (short)f2bf(d.w);
      *(bf16x8*)(wout + g8) = p;
    }
    if (g8 < 1024 * KIN) {
      const int r = g8 / KIN, c0 = g8 - r * KIN;
      bf16x8 o;
      if (c0 < 536) {
        const float* src = W_in + (size_t)r * 536 + c0;
        const float4 a = *(const float4*)(src);
        const float4 b = *(const float4*)(src + 4);
        o[0] = (short)f2bf(a.x); o[1] = (short)f2bf(a.y);
        o[2] = (short)f2bf(a.z); o[3] = (short)f2bf(a.w);
        o[4] = (short)f2bf(b.x); o[5] = (short)f2bf(b.y);
        o[6] = (short)f2bf(b.z); o[7] = (short)f2bf(b.w);
      } else {
        o = (bf16x8)(short)0;
      }
      *(bf16x8*)(win + g8) = o;
    }
    if (wgid < 1024) bqk[wgid] = wgid < 512 ? bq[wgid] : bk[wgid - 512];
    return;
  }
  // ------- dual LN: wave-per-row (4096 blocks x 4 rows) -------
  const int row = (blockIdx.x - 1312) * 4 + (threadIdx.x >> 6);
  const int l = threadIdx.x & 63;
  const float* xr = x + (size_t)row * D + l * 8;
  const float4 v0 = *(const float4*)(xr);
  const float4 v1 = *(const float4*)(xr + 4);
  float s  = v0.x + v0.y + v0.z + v0.w + v1.x + v1.y + v1.z + v1.w;
  float s2 = v0.x * v0.x + v0.y * v0.y + v0.z * v0.z + v0.w * v0.w
           + v1.x * v1.x + v1.y * v1.y + v1.z * v1.z + v1.w * v1.w;
#pragma unroll
  for (int m = 1; m < 64; m <<= 1) {
    s  += __shfl_xor(s, m, 64);
    s2 += __shfl_xor(s2, m, 64);
  }
  const float mu = s * (1.f / D);
  const float var = s2 * (1.f / D) - mu * mu;
  const float rs = rsqrtf(var + 1e-5f);
  const int c0 = l * 8;
  const float4 ga0 = *(const float4*)(g1 + c0), ga1 = *(const float4*)(g1 + c0 + 4);
  const float4 ba0 = *(const float4*)(b1 + c0), ba1 = *(const float4*)(b1 + c0 + 4);
  const float4 gm0 = *(const float4*)(g2 + c0), gm1 = *(const float4*)(g2 + c0 + 4);
  const float4 bm0 = *(const float4*)(b2 + c0), bm1 = *(const float4*)(b2 + c0 + 4);
  const float n[8] = { (v0.x - mu) * rs, (v0.y - mu) * rs, (v0.z - mu) * rs, (v0.w - mu) * rs,
                       (v1.x - mu) * rs, (v1.y - mu) * rs, (v1.z - mu) * rs, (v1.w - mu) * rs };
  const float ga[8] = { ga0.x, ga0.y, ga0.z, ga0.w, ga1.x, ga1.y, ga1.z, ga1.w };
  const float ba[8] = { ba0.x, ba0.y, ba0.z, ba0.w, ba1.x, ba1.y, ba1.z, ba1.w };
  const float gm[8] = { gm0.x, gm0.y, gm0.z, gm0.w, gm1.x, gm1.y, gm1.z, gm1.w };
  const float bm[8] = { bm0.x, bm0.y, bm0.z, bm0.w, bm1.x, bm1.y, bm1.z, bm1.w };
  bf16x8 za, zc;
#pragma unroll
  for (int i = 0; i < 8; ++i) {
    za[i] = (short)f2bf(n[i] * ga[i] + ba[i]);
    zc[i] = (short)f2bf(n[i] * gm[i] + bm[i]);
  }
  *(bf16x8*)(zatt + (size_t)row * D + c0) = za;
  *(bf16x8*)(zcat + (size_t)row * KIN + c0) = zc;
  if (l < 32) ((unsigned int*)(zcat + (size_t)row * KIN + D))[l] = 0;  // feat+pad zero
}

// ---------------------------------------------------------------- 256^2 8-wave deep-pipelined NT GEMM
#define MM_BLK(AF, BF, NB) do {                                               \
  __builtin_amdgcn_s_setprio(1);                                              \
  _Pragma("unroll")                                                           \
  for (int mi = 0; mi < 8; ++mi) {                                            \
    acc[mi][NB]     = __builtin_amdgcn_mfma_f32_16x16x32_bf16(AF[mi], BF[0], acc[mi][NB], 0, 0, 0);     \
    acc[mi][NB + 1] = __builtin_amdgcn_mfma_f32_16x16x32_bf16(AF[mi], BF[1], acc[mi][NB + 1], 0, 0, 0); \
  }                                                                           \
  __builtin_amdgcn_s_setprio(0);                                              \
} while (0)

template <int EPI>
__global__ __launch_bounds__(512, 2) void gemm256(
    const u16* __restrict__ A, const u16* __restrict__ B,
    const float* __restrict__ bias,
    void* __restrict__ Cout, int M, int Nn, int K)
{
  extern __shared__ __align__(16) u16 lds[];   // 65536 u16 = 128 KiB
  const int tid = threadIdx.x;
  const int lane = tid & 63;
  const int wave = tid >> 6;          // 0..7
  const int wave_m = wave >> 2;
  const int wave_n = wave & 3;
  const int m0 = blockIdx.x * 256;
  const int n0 = blockIdx.y * 256;
  const int fr = lane & 15;
  const int fq = lane >> 4;
  const int NT = K >> 6;
  const int sw = (fq ^ ((fr >> 1) & 3)) * 8;

  f32x4 acc[8][4];
#pragma unroll
  for (int i = 0; i < 8; ++i)
#pragma unroll
    for (int j = 0; j < 4; ++j) acc[i][j] = 0.f;

  auto stageA = [&](int slot, int ktile, int kh) {
    u16* base = lds + slot * 8192;
    const int kb = ktile * 64 + kh * 32;
#pragma unroll
    for (int r = 0; r < 2; ++r) {
      const int g = r * 512 + tid;
      const int row = g >> 2;
      const int gs = (g & 3) ^ ((row >> 1) & 3);
      gload16(A + (size_t)(m0 + row) * K + kb + gs * 8,
              base + (r * 512 + wave * 64) * 8);
    }
  };
  auto stageB = [&](int slot, int ktile, int kh) {
    u16* base = lds + 32768 + slot * 8192;
    const int kb = ktile * 64 + kh * 32;
#pragma unroll
    for (int r = 0; r < 2; ++r) {
      const int g = r * 512 + tid;
      const int row = g >> 2;
      const int gs = (g & 3) ^ ((row >> 1) & 3);
      gload16(B + (size_t)(n0 + row) * K + kb + gs * 8,
              base + (r * 512 + wave * 64) * 8);
    }
  };
  auto ldA = [&](bf16x8 (&af)[8], int slot) {
    const u16* p = lds + slot * 8192 + (wave_m * 128 + fr) * 32 + sw;
#pragma unroll
    for (int mi = 0; mi < 8; ++mi)
      af[mi] = *(const bf16x8*)(p + mi * 16 * 32);
  };
  auto ldB = [&](bf16x8 (&bf)[2], int slot, int nh) {
    const u16* p = lds + 32768 + slot * 8192 + (wave_n * 64 + nh * 32 + fr) * 32 + sw;
    bf[0] = *(const bf16x8*)(p);
    bf[1] = *(const bf16x8*)(p + 16 * 32);
  };

  stageA(0, 0, 0); stageB(0, 0, 0);
  stageA(1, 0, 1); stageB(1, 0, 1);
  stageA(2, 1, 0); stageB(2, 1, 0);
  stageA(3, 1, 1);
  asm volatile("s_waitcnt vmcnt(10)" ::: "memory");
  __builtin_amdgcn_s_barrier();
  asm volatile("" ::: "memory");

  bf16x8 af[8], bf0[2], bf1[2];
  for (int t = 0; t < NT; ++t) {
    const int sa0 = (2 * t) & 3,  sa1 = (2 * t + 1) & 3;
    const int sb1n = (2 * t + 3) & 3;
    const int t1 = (t + 1 >= NT) ? t + 1 - NT : t + 1;
    const int t2 = (t + 2 >= NT) ? t + 2 - NT : t + 2;

    ldA(af, sa0); ldB(bf0, sa0, 0);
    stageB(sb1n, t1, 1);
    __builtin_amdgcn_s_barrier();
    asm volatile("" ::: "memory");
    MM_BLK(af, bf0, 0);
    __builtin_amdgcn_s_barrier();
    asm volatile("" ::: "memory");
    ldB(bf1, sa0, 1);
    stageA(sa0, t2, 0);
    __builtin_amdgcn_s_barrier();
    asm volatile("" ::: "memory");
    MM_BLK(af, bf1, 2);
    asm volatile("s_waitcnt vmcnt(10)" ::: "memory");
    __builtin_amdgcn_s_barrier();
    asm volatile("" ::: "memory");
    ldA(af, sa1); ldB(bf0, sa1, 0);
    stageB(sa0, t2, 0);
    __builtin_amdgcn_s_barrier();
    asm volatile("" ::: "memory");
    MM_BLK(af, bf0, 0);
    __builtin_amdgcn_s_barrier();
    asm volatile("" ::: "memory");
    ldB(bf1, sa1, 1);
    stageA(sa1, t2, 1);
    __builtin_amdgcn_s_barrier();
    asm volatile("" ::: "memory");
    MM_BLK(af, bf1, 2);
    asm volatile("s_waitcnt vmcnt(10)" ::: "memory");
    __builtin_amdgcn_s_barrier();
    asm volatile("" ::: "memory");
  }
  asm volatile("s_waitcnt vmcnt(0)" ::: "memory");

#pragma unroll
  for (int mi = 0; mi < 8; ++mi) {
#pragma unroll
    for (int nj = 0; nj < 4; ++nj) {
      const int col = n0 + wave_n * 64 + nj * 16 + fr;
      const float bv = bias[col];
#pragma unroll
      for (int rr = 0; rr < 4; ++rr) {
        const int row = m0 + wave_m * 128 + mi * 16 + fq * 4 + rr;
        float v = acc[mi][nj][rr] + bv;
        if (EPI == 1) {
          const float nu = -1.5957691216057308f * (v + 0.044715f * v * v * v);
          const float sg = __builtin_amdgcn_rcpf(1.f + __expf(nu));
          ((u16*)Cout)[(size_t)row * Nn + col] = f2bf(v * sg);
        } else {
          const int pk = __builtin_amdgcn_cvt_pk_fp8_f32(v, v, 0, false);
          ((unsigned char*)Cout)[(size_t)row * Nn + col] = (unsigned char)(pk & 0xFF);
        }
      }
    }
  }
}

// ---------------------------------------------------------------- gemm3: deep-pipelined BM=256 x BN=128 (grid 64x4 = 1/CU)
__global__ __launch_bounds__(512, 2) void gemm_mlp(
    const u16* __restrict__ A, const u16* __restrict__ B,
    const float* __restrict__ bias, const float* __restrict__ resid,
    float* __restrict__ Cout, int M, int Nn, int K)
{
  extern __shared__ __align__(16) u16 lds[];   // A: 4 x 8192 u16; B: 4 x 4096 u16 at +32768
  const int tid = threadIdx.x;
  const int lane = tid & 63;
  const int wave = tid >> 6;
  const int wave_m = wave >> 2;       // 0..1
  const int wave_n = wave & 3;        // 0..3
  const int m0 = blockIdx.x * 256;
  const int n0 = blockIdx.y * 128;
  const int fr = lane & 15;
  const int fq = lane >> 4;
  const int NT = K >> 6;              // 16
  const int sw = (fq ^ ((fr >> 1) & 3)) * 8;

  f32x4 acc[8][2];
#pragma unroll
  for (int i = 0; i < 8; ++i) { acc[i][0] = 0.f; acc[i][1] = 0.f; }

  auto stageA = [&](int slot, int ktile, int kh) {     // [256][32], 2 gloads
    u16* base = lds + slot * 8192;
    const int kb = ktile * 64 + kh * 32;
#pragma unroll
    for (int r = 0; r < 2; ++r) {
      const int g = r * 512 + tid;
      const int row = g >> 2;
      const int gs = (g & 3) ^ ((row >> 1) & 3);
      gload16(A + (size_t)(m0 + row) * K + kb + gs * 8,
              base + (r * 512 + wave * 64) * 8);
    }
  };
  auto stageB = [&](int slot, int ktile, int kh) {     // [128][32], 1 gload
    u16* base = lds + 32768 + slot * 4096;
    const int kb = ktile * 64 + kh * 32;
    const int row = tid >> 2;
    const int gs = (tid & 3) ^ ((row >> 1) & 3);
    gload16(B + (size_t)(n0 + row) * K + kb + gs * 8,
            base + (wave * 64 + lane) * 8);
  };
  auto ldA = [&](bf16x8 (&af)[8], int slot) {
    const u16* p = lds + slot * 8192 + (wave_m * 128 + fr) * 32 + sw;
#pragma unroll
    for (int mi = 0; mi < 8; ++mi)
      af[mi] = *(const bf16x8*)(p + mi * 16 * 32);
  };
  auto ldB2 = [&](bf16x8 (&bf)[2], int slot) {
    const u16* p = lds + 32768 + slot * 4096 + (wave_n * 32 + fr) * 32 + sw;
    bf[0] = *(const bf16x8*)(p);
    bf[1] = *(const bf16x8*)(p + 16 * 32);
  };

  stageA(0, 0, 0); stageB(0, 0, 0);
  stageA(1, 0, 1); stageB(1, 0, 1);
  stageA(2, 1, 0); stageB(2, 1, 0);
  asm volatile("s_waitcnt vmcnt(6)" ::: "memory");
  __builtin_amdgcn_s_barrier();
  asm volatile("" ::: "memory");

  bf16x8 af[8], bf[2];
  for (int t = 0; t < NT; ++t) {
    const int sa0 = (2 * t) & 3, sa1 = (2 * t + 1) & 3;
    const int sn  = (2 * t + 3) & 3;
    const int t1 = (t + 1 >= NT) ? t + 1 - NT : t + 1;
    const int t2 = (t + 2 >= NT) ? t + 2 - NT : t + 2;

    ldA(af, sa0); ldB2(bf, sa0);
    stageA(sn, t1, 1); stageB(sn, t1, 1);
    __builtin_amdgcn_s_barrier();
    asm volatile("" ::: "memory");
    MM_BLK(af, bf, 0);
    asm volatile("s_waitcnt vmcnt(6)" ::: "memory");
    __builtin_amdgcn_s_barrier();
    asm volatile("" ::: "memory");
    ldA(af, sa1); ldB2(bf, sa1);
    stageA(sa0, t2, 0); stageB(sa0, t2, 0);
    __builtin_amdgcn_s_barrier();
    asm volatile("" ::: "memory");
    MM_BLK(af, bf, 0);
    asm volatile("s_waitcnt vmcnt(6)" ::: "memory");
    __builtin_amdgcn_s_barrier();
    asm volatile("" ::: "memory");
  }
  asm volatile("s_waitcnt vmcnt(0)" ::: "memory");

#pragma unroll
  for (int mi = 0; mi < 8; ++mi) {
#pragma unroll
    for (int nj = 0; nj < 2; ++nj) {
      const int col = n0 + wave_n * 32 + nj * 16 + fr;
      const float bv = bias[col];
#pragma unroll
      for (int rr = 0; rr < 4; ++rr) {
        const int row = m0 + wave_m * 128 + mi * 16 + fq * 4 + rr;
        Cout[(size_t)row * Nn + col] = acc[mi][nj][rr] + bv + resid[(size_t)row * Nn + col];
      }
    }
  }
}

// ---------------------------------------------------------------- edge pass (bucket CSR + edge records)
// 4-stage pipeline: bucket@i+4, rec@i+3, kv@i+2, compute@i.
// Dot product: 4 parallel 4-deep fmaf chains + tree combine.
__global__ __launch_bounds__(256) void edge_csr(
    const unsigned char* __restrict__ qk8, const float* __restrict__ rec,
    const int* __restrict__ cntp, const int* __restrict__ bucket,
    const float* __restrict__ pos, u16* __restrict__ zcat)
{
  const int lane = threadIdx.x & 63;
  const int wave = threadIdx.x >> 6;
  const int row = blockIdx.x * 4 + wave;
  const int half = lane >> 5;
  const int sub = lane & 31;
  const int h = sub >> 2, j = sub & 3;
  const int deg = min(cntp[row * 16], 64);
  const int base = row * 64;

  const uint4 qv = *(const uint4*)(qk8 + (size_t)row * 1024 + sub * 16);
  float qf[16];
  {
    const unsigned int* qu = (const unsigned int*)&qv;
#pragma unroll
    for (int i = 0; i < 4; ++i) {
      const f32x2 lo = __builtin_amdgcn_cvt_pk_f32_fp8(qu[i], false);
      const f32x2 hi = __builtin_amdgcn_cvt_pk_f32_fp8(qu[i], true);
      qf[i * 4 + 0] = lo.x; qf[i * 4 + 1] = lo.y;
      qf[i * 4 + 2] = hi.x; qf[i * 4 + 3] = hi.y;
    }
  }

  float accA = 0.f, accB = 0.f;
  const int npair = (deg + 1) >> 1;

  bool ok0 = half < deg;
  int e0 = ok0 ? bucket[base + half] : 0;
  const float* r0 = rec + (size_t)e0 * 16;
  float bias0 = r0[h], invd0 = r0[8];
  float spA0 = (j >= 2) ? r0[7 + j] : 0.f;
  float spB0 = (j == 1) ? r0[11] : 0.f;
  uint4 kv0 = *(const uint4*)(qk8 + (size_t)__float_as_int(r0[12]) * 1024 + 512 + sub * 16);

  bool ok1 = 2 + half < deg;
  int e1 = ok1 ? bucket[base + 2 + half] : 0;
  const float* r1 = rec + (size_t)e1 * 16;
  float bias1 = r1[h], invd1 = r1[8];
  float spA1 = (j >= 2) ? r1[7 + j] : 0.f;
  float spB1 = (j == 1) ? r1[11] : 0.f;
  uint4 kv1 = *(const uint4*)(qk8 + (size_t)__float_as_int(r1[12]) * 1024 + 512 + sub * 16);

  bool ok2 = 4 + half < deg;
  int e2 = ok2 ? bucket[base + 4 + half] : 0;
  const float* r2p = rec + (size_t)e2 * 16;
  float bias2 = r2p[h], invd2 = r2p[8];
  float spA2 = (j >= 2) ? r2p[7 + j] : 0.f;
  float spB2 = (j == 1) ? r2p[11] : 0.f;
  int kr2 = __float_as_int(r2p[12]);

  bool ok3 = 6 + half < deg;
  int e3 = ok3 ? bucket[base + 6 + half] : 0;

  for (int i = 0; i < npair; ++i) {
    const uint4 kv2 = *(const uint4*)(qk8 + (size_t)kr2 * 1024 + 512 + sub * 16);
    const float* r3 = rec + (size_t)e3 * 16;
    const float bias3 = r3[h], invd3 = r3[8];
    const float spA3 = (j >= 2) ? r3[7 + j] : 0.f;
    const float spB3 = (j == 1) ? r3[11] : 0.f;
    const int kr3 = __float_as_int(r3[12]);
    const bool ok4 = 2 * (i + 4) + half < deg;
    const int e4 = ok4 ? bucket[base + 2 * (i + 4) + half] : 0;

    float p;
    {
      const unsigned int* ku = (const unsigned int*)&kv0;
      const f32x2 a0 = __builtin_amdgcn_cvt_pk_f32_fp8(ku[0], false);
      const f32x2 a1 = __builtin_amdgcn_cvt_pk_f32_fp8(ku[0], true);
      const f32x2 b0 = __builtin_amdgcn_cvt_pk_f32_fp8(ku[1], false);
      const f32x2 b1 = __builtin_amdgcn_cvt_pk_f32_fp8(ku[1], true);
      const f32x2 c0 = __builtin_amdgcn_cvt_pk_f32_fp8(ku[2], false);
      const f32x2 c1 = __builtin_amdgcn_cvt_pk_f32_fp8(ku[2], true);
      const f32x2 d0 = __builtin_amdgcn_cvt_pk_f32_fp8(ku[3], false);
      const f32x2 d1 = __builtin_amdgcn_cvt_pk_f32_fp8(ku[3], true);
      float pA = qf[0] * a0.x;
      float pB = qf[4] * b0.x;
      float pC = qf[8] * c0.x;
      float pD = qf[12] * d0.x;
      pA = fmaf(qf[1],  a0.y, pA);  pB = fmaf(qf[5],  b0.y, pB);
      pC = fmaf(qf[9],  c0.y, pC);  pD = fmaf(qf[13], d0.y, pD);
      pA = fmaf(qf[2],  a1.x, pA);  pB = fmaf(qf[6],  b1.x, pB);
      pC = fmaf(qf[10], c1.x, pC);  pD = fmaf(qf[14], d1.x, pD);
      pA = fmaf(qf[3],  a1.y, pA);  pB = fmaf(qf[7],  b1.y, pB);
      pC = fmaf(qf[11], c1.y, pC);  pD = fmaf(qf[15], d1.y, pD);
      p = (pA + pB) + (pC + pD);
    }
    p += __shfl_xor(p, 1, 64);
    p += __shfl_xor(p, 2, 64);
    float pe = __expf(p * 0.125f + bias0);
    pe = ok0 ? pe : 0.f;
    const float w = pe * invd0;
    accA += (j == 0) ? pe : (j == 1) ? w : w * spA0;
    accB += w * spB0;

    ok0 = ok1; bias0 = bias1; invd0 = invd1; spA0 = spA1; spB0 = spB1; kv0 = kv1;
    ok1 = ok2; bias1 = bias2; invd1 = invd2; spA1 = spA2; spB1 = spB2; kv1 = kv2;
    ok2 = ok3; bias2 = bias3; invd2 = invd3; spA2 = spA3; spB2 = spB3; kr2 = kr3;
    ok3 = ok4; e3 = e4;
  }

  accA += __shfl_xor(accA, 32, 64);
  accB += __shfl_xor(accB, 32, 64);
  const int hb = h << 2;
  const float den  = __shfl(accA, hb + 0, 64);
  const float wsum = __shfl(accA, hb + 1, 64);
  const float wsp01 = __shfl(accA, hb + 2 + (j & 1), 64);
  const float wsp2  = __shfl(accB, hb + 1, 64);
  const float invd = (den != 0.f) ? 1.f / den : 0.f;
  const float rsum = wsum * invd;
  if (half == 0 && j < 3) {
    const float wspj = (j < 2) ? wsp01 : wsp2;
    zcat[(size_t)row * KIN + D + h * 3 + j] = f2bf(wspj * invd - rsum * pos[row * 3 + j]);
  }
}

// ---------------------------------------------------------------- launch
extern "C" void kernel_launch(void* const* d_in, const int* in_sizes, int n_in,
                              void* d_out, int out_size, void* d_ws, size_t ws_size,
                              hipStream_t stream)
{
  const float* x        = (const float*)d_in[0];
  const float* Wq       = (const float*)d_in[1];
  const float* bq       = (const float*)d_in[2];
  const float* Wk       = (const float*)d_in[3];
  const float* bk       = (const float*)d_in[4];
  const float* g_att    = (const float*)d_in[5];
  const float* b_att    = (const float*)d_in[6];
  const float* g_mlp    = (const float*)d_in[7];
  const float* b_mlp    = (const float*)d_in[8];
  const float* W_in     = (const float*)d_in[9];
  const float* b_in     = (const float*)d_in[10];
  const float* W_out    = (const float*)d_in[11];
  const float* b_out    = (const float*)d_in[12];
  const float* att_bias = (const float*)d_in[13];
  const float* dist     = (const float*)d_in[14];
  const float* pos      = (const float*)d_in[15];
  const float* src_pos  = (const float*)d_in[16];
  const int* row_index  = (const int*)d_in[17];
  const int* src_index  = (const int*)d_in[18];
  const int* org_to_src = (const int*)d_in[19];

  char* ws = (char*)d_ws;
  u16*   zatt = (u16*)(ws + OFF_ZATT);
  u16*   zcat = (u16*)(ws + OFF_ZCAT);
  u16*   wqk  = (u16*)(ws + OFF_WQK);
  float* bqk  = (float*)(ws + OFF_BQK);
  u16*   win  = (u16*)(ws + OFF_WIN);
  u16*   wout = (u16*)(ws + OFF_WOUT);
  unsigned char* qk8 = (unsigned char*)(ws + OFF_QK);
  int*   bkt  = (int*)(ws + OFF_BKT);
  u16*   hbf  = (u16*)(ws + OFF_HBF);
  float* rec  = (float*)(ws + OFF_REC);
  int*   cntp = (int*)(ws + OFF_CNTP);

  static bool s_attr = false;
  if (!s_attr) {
    hipFuncSetAttribute(reinterpret_cast<const void*>(&gemm256<4>),
                        hipFuncAttributeMaxDynamicSharedMemorySize, 131072);
    hipFuncSetAttribute(reinterpret_cast<const void*>(&gemm256<1>),
                        hipFuncAttributeMaxDynamicSharedMemorySize, 131072);
    hipFuncSetAttribute(reinterpret_cast<const void*>(&gemm_mlp),
                        hipFuncAttributeMaxDynamicSharedMemorySize, 98304);
    s_attr = true;
  }

  hipMemsetAsync(ws + OFF_CNTP, 0, 16384 * 64, stream);

  prep_all<<<1024 + 288 + 4096, 256, 0, stream>>>(
      row_index, att_bias, dist, src_pos, src_index, org_to_src, cntp, bkt, rec,
      Wq, Wk, bq, bk, W_in, W_out, wqk, bqk, win, wout,
      x, g_att, b_att, g_mlp, b_mlp, zatt, zcat);
  gemm256<4><<<dim3(64, 4), 512, 131072, stream>>>(zatt, wqk, bqk, qk8, N_NODES, 1024, 512);
  edge_csr<<<N_NODES / 4, 256, 0, stream>>>(qk8, rec, cntp, bkt, pos, zcat);
  gemm256<1><<<dim3(64, 4), 512, 131072, stream>>>(zcat, win, b_in, hbf, N_NODES, 1024, KIN);
  gemm_mlp<<<dim3(64, 4), 512, 98304, stream>>>(hbf, wout, b_out, x, (float*)d_out, N_NODES, 512, 1024);
}

// Round 11
// 250.179 us; speedup vs baseline: 1.0337x; 1.0077x over previous
//
#include <hip/hip_runtime.h>
#include <math.h>

// PositionFeaturizer on MI355X — round 18:
//  * Single lever: edge-segment rec writes were 4x float4 at 64-B lane
//    stride (64 lines touched per store instr, partial-line assembly at L2;
//    WRITE_SIZE 12MB over hand count). Now staged through LDS (stride-17
//    rows: write conflict-free, read 2-way=free) and written as 4 fully
//    coalesced float4 stores (16B/lane contiguous). 17KB static LDS caps
//    at 9 blocks/CU > 8-block wave cap -> no occupancy cost.
//  * Everything else byte-identical to r17 (252.1 best).

typedef unsigned short u16;
typedef __attribute__((ext_vector_type(8))) short bf16x8;   // 8 bf16 in 4 VGPRs
typedef __attribute__((ext_vector_type(4))) float f32x4;
typedef __attribute__((ext_vector_type(2))) float f32x2;

constexpr int N_NODES = 16384;
constexpr int E_EDGES = 262144;
constexpr int D = 512;
constexpr int KIN = 576;    // 536 padded to 9*64

// workspace layout (bytes)
constexpr size_t OFF_ZATT = 0;                       // 16384*512*2  = 16,777,216
constexpr size_t OFF_ZCAT = 16777216;                // 16384*576*2  = 18,874,368
constexpr size_t OFF_WQK  = 35651584;                // 1024*512*2   = 1,048,576
constexpr size_t OFF_BQK  = 36700160;                // 1024*4       = 4,096
constexpr size_t OFF_WIN  = 36704256;                // 1024*576*2   = 1,179,648
constexpr size_t OFF_WOUT = 37883904;                // 512*1024*2   = 1,048,576
constexpr size_t OFF_QK   = 38932480;                // 16384*1024*1 = 16,777,216 (fp8)
constexpr size_t OFF_BKT  = 55775232;                // 16384*64*4 = 4,194,304
constexpr size_t OFF_HBF  = 59969536;                // 16384*1024*2 = 33,554,432
constexpr size_t OFF_REC  = 93523968;                // 262144*64 = 16,777,216
constexpr size_t OFF_CNTP = 110301184;               // 16384*64 = 1,048,576

static __device__ __forceinline__ u16 f2bf(float f) {
  union { float f; unsigned int u; } v; v.f = f;
  unsigned int u = v.u;
  u = u + 0x7FFFu + ((u >> 16) & 1u);   // RNE
  return (u16)(u >> 16);
}
// async global->LDS, 16 B per lane; LDS dest = wave-uniform base + lane*16
static __device__ __forceinline__ void gload16(const u16* g, u16* l) {
  __builtin_amdgcn_global_load_lds(
      (const __attribute__((address_space(1))) unsigned int*)g,
      (__attribute__((address_space(3))) unsigned int*)l, 16, 0, 0);
}

// ---------------------------------------------------------------- fused prep: edges + weights + dual LN
// blocks [0,1024): edge records+CSR, 1 edge/thread, LDS-coalesced rec write
// blocks [1024,1312): weight casts, 8 elems/thread (vectorized)
// blocks [1312,5408): dual LN, wave-per-row (4 rows/block)
__global__ __launch_bounds__(256) void prep_all(
    const int* __restrict__ row_index,
    const float* __restrict__ att_bias, const float* __restrict__ dist,
    const float* __restrict__ src_pos, const int* __restrict__ src_index,
    const int* __restrict__ org_to_src,
    int* __restrict__ cntp, int* __restrict__ bucket, float* __restrict__ rec,
    const float* __restrict__ Wq, const float* __restrict__ Wk,
    const float* __restrict__ bq, const float* __restrict__ bk,
    const float* __restrict__ W_in, const float* __restrict__ W_out,
    u16* __restrict__ wqk, float* __restrict__ bqk,
    u16* __restrict__ win, u16* __restrict__ wout,
    const float* __restrict__ x,
    const float* __restrict__ g1, const float* __restrict__ b1,
    const float* __restrict__ g2, const float* __restrict__ b2,
    u16* __restrict__ zatt, u16* __restrict__ zcat)
{
  __shared__ float sb[256 * 17];   // 17 KB: stride-17 rows -> bank-conflict-free
  if (blockIdx.x < 1024) {
    // ------- edge records + bucket CSR: 1 edge/thread -------
    const int tid = threadIdx.x;
    const int gid = blockIdx.x * 256 + tid;   // < E_EDGES
    const int r = row_index[gid];
    const int s = src_index[gid];
    const float dv = dist[gid];
    float rv[16];
    rv[0] = att_bias[gid];
    rv[1] = att_bias[(size_t)1 * E_EDGES + gid];
    rv[2] = att_bias[(size_t)2 * E_EDGES + gid];
    rv[3] = att_bias[(size_t)3 * E_EDGES + gid];
    rv[4] = att_bias[(size_t)4 * E_EDGES + gid];
    rv[5] = att_bias[(size_t)5 * E_EDGES + gid];
    rv[6] = att_bias[(size_t)6 * E_EDGES + gid];
    rv[7] = att_bias[(size_t)7 * E_EDGES + gid];
    rv[8] = (dv == 0.f) ? 0.f : 1.f / dv;   // matches ref: inv = 1/dist, then mul
    rv[9]  = src_pos[(size_t)s * 3 + 0];
    rv[10] = src_pos[(size_t)s * 3 + 1];
    rv[11] = src_pos[(size_t)s * 3 + 2];
    rv[12] = __int_as_float(org_to_src[s]);
    rv[13] = 0.f; rv[14] = 0.f; rv[15] = 0.f;
#pragma unroll
    for (int k = 0; k < 16; ++k) sb[tid * 17 + k] = rv[k];
    const int p = atomicAdd(&cntp[r * 16], 1);   // 1 counter per 64-B line
    if (p < 64) bucket[(size_t)r * 64 + p] = gid;
    __syncthreads();
    // coalesced writeback: 256 edges x 64B chunk, 16B/lane contiguous
    const size_t cb = (size_t)blockIdx.x * 4096;   // floats per chunk
#pragma unroll
    for (int k = 0; k < 4; ++k) {
      const int f = tid * 4 + k * 1024;
      const int e = f >> 4, c = f & 15;
      float4 v;
      v.x = sb[e * 17 + c];     v.y = sb[e * 17 + c + 1];
      v.z = sb[e * 17 + c + 2]; v.w = sb[e * 17 + c + 3];
      *(float4*)(rec + cb + f) = v;
    }
    return;
  }
  if (blockIdx.x < 1312) {
    // ------- weight casts: 8 elems/thread (all boundaries %8==0) -------
    const int wgid = (blockIdx.x - 1024) * 256 + threadIdx.x;
    const int g8 = wgid * 8;
    if (g8 < 512 * 1024) {
      const float* src = (g8 < 512 * 512) ? (Wq + g8) : (Wk + g8 - 512 * 512);
      const float4 a = *(const float4*)(src);
      const float4 b = *(const float4*)(src + 4);
      bf16x8 o;
      o[0] = (short)f2bf(a.x); o[1] = (short)f2bf(a.y);
      o[2] = (short)f2bf(a.z); o[3] = (short)f2bf(a.w);
      o[4] = (short)f2bf(b.x); o[5] = (short)f2bf(b.y);
      o[6] = (short)f2bf(b.z); o[7] = (short)f2bf(b.w);
      *(bf16x8*)(wqk + g8) = o;
      const float4 c = *(const float4*)(W_out + g8);
      const float4 d = *(const float4*)(W_out + g8 + 4);
      bf16x8 p;
      p[0] = (short)f2bf(c.x); p[1] = (short)f2bf(c.y);
      p[2] = (short)f2bf(c.z); p[3] = (short)f2bf(c.w);
      p[4] = (short)f2bf(d.x); p[5] = (short)f2bf(d.y);
      p[6] = (short)f2bf(d.z); p[7] = (short)f2bf(d.w);
      *(bf16x8*)(wout + g8) = p;
    }
    if (g8 < 1024 * KIN) {
      const int r = g8 / KIN, c0 = g8 - r * KIN;
      bf16x8 o;
      if (c0 < 536) {
        const float* src = W_in + (size_t)r * 536 + c0;
        const float4 a = *(const float4*)(src);
        const float4 b = *(const float4*)(src + 4);
        o[0] = (short)f2bf(a.x); o[1] = (short)f2bf(a.y);
        o[2] = (short)f2bf(a.z); o[3] = (short)f2bf(a.w);
        o[4] = (short)f2bf(b.x); o[5] = (short)f2bf(b.y);
        o[6] = (short)f2bf(b.z); o[7] = (short)f2bf(b.w);
      } else {
        o = (bf16x8)(short)0;
      }
      *(bf16x8*)(win + g8) = o;
    }
    if (wgid < 1024) bqk[wgid] = wgid < 512 ? bq[wgid] : bk[wgid - 512];
    return;
  }
  // ------- dual LN: wave-per-row (4096 blocks x 4 rows) -------
  const int row = (blockIdx.x - 1312) * 4 + (threadIdx.x >> 6);
  const int l = threadIdx.x & 63;
  const float* xr = x + (size_t)row * D + l * 8;
  const float4 v0 = *(const float4*)(xr);
  const float4 v1 = *(const float4*)(xr + 4);
  float s  = v0.x + v0.y + v0.z + v0.w + v1.x + v1.y + v1.z + v1.w;
  float s2 = v0.x * v0.x + v0.y * v0.y + v0.z * v0.z + v0.w * v0.w
           + v1.x * v1.x + v1.y * v1.y + v1.z * v1.z + v1.w * v1.w;
#pragma unroll
  for (int m = 1; m < 64; m <<= 1) {
    s  += __shfl_xor(s, m, 64);
    s2 += __shfl_xor(s2, m, 64);
  }
  const float mu = s * (1.f / D);
  const float var = s2 * (1.f / D) - mu * mu;
  const float rs = rsqrtf(var + 1e-5f);
  const int c0 = l * 8;
  const float4 ga0 = *(const float4*)(g1 + c0), ga1 = *(const float4*)(g1 + c0 + 4);
  const float4 ba0 = *(const float4*)(b1 + c0), ba1 = *(const float4*)(b1 + c0 + 4);
  const float4 gm0 = *(const float4*)(g2 + c0), gm1 = *(const float4*)(g2 + c0 + 4);
  const float4 bm0 = *(const float4*)(b2 + c0), bm1 = *(const float4*)(b2 + c0 + 4);
  const float n[8] = { (v0.x - mu) * rs, (v0.y - mu) * rs, (v0.z - mu) * rs, (v0.w - mu) * rs,
                       (v1.x - mu) * rs, (v1.y - mu) * rs, (v1.z - mu) * rs, (v1.w - mu) * rs };
  const float ga[8] = { ga0.x, ga0.y, ga0.z, ga0.w, ga1.x, ga1.y, ga1.z, ga1.w };
  const float ba[8] = { ba0.x, ba0.y, ba0.z, ba0.w, ba1.x, ba1.y, ba1.z, ba1.w };
  const float gm[8] = { gm0.x, gm0.y, gm0.z, gm0.w, gm1.x, gm1.y, gm1.z, gm1.w };
  const float bm[8] = { bm0.x, bm0.y, bm0.z, bm0.w, bm1.x, bm1.y, bm1.z, bm1.w };
  bf16x8 za, zc;
#pragma unroll
  for (int i = 0; i < 8; ++i) {
    za[i] = (short)f2bf(n[i] * ga[i] + ba[i]);
    zc[i] = (short)f2bf(n[i] * gm[i] + bm[i]);
  }
  *(bf16x8*)(zatt + (size_t)row * D + c0) = za;
  *(bf16x8*)(zcat + (size_t)row * KIN + c0) = zc;
  if (l < 32) ((unsigned int*)(zcat + (size_t)row * KIN + D))[l] = 0;  // feat+pad zero
}

// ---------------------------------------------------------------- 256^2 8-wave deep-pipelined NT GEMM
#define MM_BLK(AF, BF, NB) do {                                               \
  __builtin_amdgcn_s_setprio(1);                                              \
  _Pragma("unroll")                                                           \
  for (int mi = 0; mi < 8; ++mi) {                                            \
    acc[mi][NB]     = __builtin_amdgcn_mfma_f32_16x16x32_bf16(AF[mi], BF[0], acc[mi][NB], 0, 0, 0);     \
    acc[mi][NB + 1] = __builtin_amdgcn_mfma_f32_16x16x32_bf16(AF[mi], BF[1], acc[mi][NB + 1], 0, 0, 0); \
  }                                                                           \
  __builtin_amdgcn_s_setprio(0);                                              \
} while (0)

template <int EPI>
__global__ __launch_bounds__(512, 2) void gemm256(
    const u16* __restrict__ A, const u16* __restrict__ B,
    const float* __restrict__ bias,
    void* __restrict__ Cout, int M, int Nn, int K)
{
  extern __shared__ __align__(16) u16 lds[];   // 65536 u16 = 128 KiB
  const int tid = threadIdx.x;
  const int lane = tid & 63;
  const int wave = tid >> 6;          // 0..7
  const int wave_m = wave >> 2;
  const int wave_n = wave & 3;
  const int m0 = blockIdx.x * 256;
  const int n0 = blockIdx.y * 256;
  const int fr = lane & 15;
  const int fq = lane >> 4;
  const int NT = K >> 6;
  const int sw = (fq ^ ((fr >> 1) & 3)) * 8;

  f32x4 acc[8][4];
#pragma unroll
  for (int i = 0; i < 8; ++i)
#pragma unroll
    for (int j = 0; j < 4; ++j) acc[i][j] = 0.f;

  auto stageA = [&](int slot, int ktile, int kh) {
    u16* base = lds + slot * 8192;
    const int kb = ktile * 64 + kh * 32;
#pragma unroll
    for (int r = 0; r < 2; ++r) {
      const int g = r * 512 + tid;
      const int row = g >> 2;
      const int gs = (g & 3) ^ ((row >> 1) & 3);
      gload16(A + (size_t)(m0 + row) * K + kb + gs * 8,
              base + (r * 512 + wave * 64) * 8);
    }
  };
  auto stageB = [&](int slot, int ktile, int kh) {
    u16* base = lds + 32768 + slot * 8192;
    const int kb = ktile * 64 + kh * 32;
#pragma unroll
    for (int r = 0; r < 2; ++r) {
      const int g = r * 512 + tid;
      const int row = g >> 2;
      const int gs = (g & 3) ^ ((row >> 1) & 3);
      gload16(B + (size_t)(n0 + row) * K + kb + gs * 8,
              base + (r * 512 + wave * 64) * 8);
    }
  };
  auto ldA = [&](bf16x8 (&af)[8], int slot) {
    const u16* p = lds + slot * 8192 + (wave_m * 128 + fr) * 32 + sw;
#pragma unroll
    for (int mi = 0; mi < 8; ++mi)
      af[mi] = *(const bf16x8*)(p + mi * 16 * 32);
  };
  auto ldB = [&](bf16x8 (&bf)[2], int slot, int nh) {
    const u16* p = lds + 32768 + slot * 8192 + (wave_n * 64 + nh * 32 + fr) * 32 + sw;
    bf[0] = *(const bf16x8*)(p);
    bf[1] = *(const bf16x8*)(p + 16 * 32);
  };

  stageA(0, 0, 0); stageB(0, 0, 0);
  stageA(1, 0, 1); stageB(1, 0, 1);
  stageA(2, 1, 0); stageB(2, 1, 0);
  stageA(3, 1, 1);
  asm volatile("s_waitcnt vmcnt(10)" ::: "memory");
  __builtin_amdgcn_s_barrier();
  asm volatile("" ::: "memory");

  bf16x8 af[8], bf0[2], bf1[2];
  for (int t = 0; t < NT; ++t) {
    const int sa0 = (2 * t) & 3,  sa1 = (2 * t + 1) & 3;
    const int sb1n = (2 * t + 3) & 3;
    const int t1 = (t + 1 >= NT) ? t + 1 - NT : t + 1;
    const int t2 = (t + 2 >= NT) ? t + 2 - NT : t + 2;

    ldA(af, sa0); ldB(bf0, sa0, 0);
    stageB(sb1n, t1, 1);
    __builtin_amdgcn_s_barrier();
    asm volatile("" ::: "memory");
    MM_BLK(af, bf0, 0);
    __builtin_amdgcn_s_barrier();
    asm volatile("" ::: "memory");
    ldB(bf1, sa0, 1);
    stageA(sa0, t2, 0);
    __builtin_amdgcn_s_barrier();
    asm volatile("" ::: "memory");
    MM_BLK(af, bf1, 2);
    asm volatile("s_waitcnt vmcnt(10)" ::: "memory");
    __builtin_amdgcn_s_barrier();
    asm volatile("" ::: "memory");
    ldA(af, sa1); ldB(bf0, sa1, 0);
    stageB(sa0, t2, 0);
    __builtin_amdgcn_s_barrier();
    asm volatile("" ::: "memory");
    MM_BLK(af, bf0, 0);
    __builtin_amdgcn_s_barrier();
    asm volatile("" ::: "memory");
    ldB(bf1, sa1, 1);
    stageA(sa1, t2, 1);
    __builtin_amdgcn_s_barrier();
    asm volatile("" ::: "memory");
    MM_BLK(af, bf1, 2);
    asm volatile("s_waitcnt vmcnt(10)" ::: "memory");
    __builtin_amdgcn_s_barrier();
    asm volatile("" ::: "memory");
  }
  asm volatile("s_waitcnt vmcnt(0)" ::: "memory");

#pragma unroll
  for (int mi = 0; mi < 8; ++mi) {
#pragma unroll
    for (int nj = 0; nj < 4; ++nj) {
      const int col = n0 + wave_n * 64 + nj * 16 + fr;
      const float bv = bias[col];
#pragma unroll
      for (int rr = 0; rr < 4; ++rr) {
        const int row = m0 + wave_m * 128 + mi * 16 + fq * 4 + rr;
        float v = acc[mi][nj][rr] + bv;
        if (EPI == 1) {
          const float nu = -1.5957691216057308f * (v + 0.044715f * v * v * v);
          const float sg = __builtin_amdgcn_rcpf(1.f + __expf(nu));
          ((u16*)Cout)[(size_t)row * Nn + col] = f2bf(v * sg);
        } else {
          const int pk = __builtin_amdgcn_cvt_pk_fp8_f32(v, v, 0, false);
          ((unsigned char*)Cout)[(size_t)row * Nn + col] = (unsigned char)(pk & 0xFF);
        }
      }
    }
  }
}

// ---------------------------------------------------------------- gemm3: deep-pipelined BM=256 x BN=128 (grid 64x4 = 1/CU)
__global__ __launch_bounds__(512, 2) void gemm_mlp(
    const u16* __restrict__ A, const u16* __restrict__ B,
    const float* __restrict__ bias, const float* __restrict__ resid,
    float* __restrict__ Cout, int M, int Nn, int K)
{
  extern __shared__ __align__(16) u16 lds[];   // A: 4 x 8192 u16; B: 4 x 4096 u16 at +32768
  const int tid = threadIdx.x;
  const int lane = tid & 63;
  const int wave = tid >> 6;
  const int wave_m = wave >> 2;       // 0..1
  const int wave_n = wave & 3;        // 0..3
  const int m0 = blockIdx.x * 256;
  const int n0 = blockIdx.y * 128;
  const int fr = lane & 15;
  const int fq = lane >> 4;
  const int NT = K >> 6;              // 16
  const int sw = (fq ^ ((fr >> 1) & 3)) * 8;

  f32x4 acc[8][2];
#pragma unroll
  for (int i = 0; i < 8; ++i) { acc[i][0] = 0.f; acc[i][1] = 0.f; }

  auto stageA = [&](int slot, int ktile, int kh) {     // [256][32], 2 gloads
    u16* base = lds + slot * 8192;
    const int kb = ktile * 64 + kh * 32;
#pragma unroll
    for (int r = 0; r < 2; ++r) {
      const int g = r * 512 + tid;
      const int row = g >> 2;
      const int gs = (g & 3) ^ ((row >> 1) & 3);
      gload16(A + (size_t)(m0 + row) * K + kb + gs * 8,
              base + (r * 512 + wave * 64) * 8);
    }
  };
  auto stageB = [&](int slot, int ktile, int kh) {     // [128][32], 1 gload
    u16* base = lds + 32768 + slot * 4096;
    const int kb = ktile * 64 + kh * 32;
    const int row = tid >> 2;
    const int gs = (tid & 3) ^ ((row >> 1) & 3);
    gload16(B + (size_t)(n0 + row) * K + kb + gs * 8,
            base + (wave * 64 + lane) * 8);
  };
  auto ldA = [&](bf16x8 (&af)[8], int slot) {
    const u16* p = lds + slot * 8192 + (wave_m * 128 + fr) * 32 + sw;
#pragma unroll
    for (int mi = 0; mi < 8; ++mi)
      af[mi] = *(const bf16x8*)(p + mi * 16 * 32);
  };
  auto ldB2 = [&](bf16x8 (&bf)[2], int slot) {
    const u16* p = lds + 32768 + slot * 4096 + (wave_n * 32 + fr) * 32 + sw;
    bf[0] = *(const bf16x8*)(p);
    bf[1] = *(const bf16x8*)(p + 16 * 32);
  };

  stageA(0, 0, 0); stageB(0, 0, 0);
  stageA(1, 0, 1); stageB(1, 0, 1);
  stageA(2, 1, 0); stageB(2, 1, 0);
  asm volatile("s_waitcnt vmcnt(6)" ::: "memory");
  __builtin_amdgcn_s_barrier();
  asm volatile("" ::: "memory");

  bf16x8 af[8], bf[2];
  for (int t = 0; t < NT; ++t) {
    const int sa0 = (2 * t) & 3, sa1 = (2 * t + 1) & 3;
    const int sn  = (2 * t + 3) & 3;
    const int t1 = (t + 1 >= NT) ? t + 1 - NT : t + 1;
    const int t2 = (t + 2 >= NT) ? t + 2 - NT : t + 2;

    ldA(af, sa0); ldB2(bf, sa0);
    stageA(sn, t1, 1); stageB(sn, t1, 1);
    __builtin_amdgcn_s_barrier();
    asm volatile("" ::: "memory");
    MM_BLK(af, bf, 0);
    asm volatile("s_waitcnt vmcnt(6)" ::: "memory");
    __builtin_amdgcn_s_barrier();
    asm volatile("" ::: "memory");
    ldA(af, sa1); ldB2(bf, sa1);
    stageA(sa0, t2, 0); stageB(sa0, t2, 0);
    __builtin_amdgcn_s_barrier();
    asm volatile("" ::: "memory");
    MM_BLK(af, bf, 0);
    asm volatile("s_waitcnt vmcnt(6)" ::: "memory");
    __builtin_amdgcn_s_barrier();
    asm volatile("" ::: "memory");
  }
  asm volatile("s_waitcnt vmcnt(0)" ::: "memory");

#pragma unroll
  for (int mi = 0; mi < 8; ++mi) {
#pragma unroll
    for (int nj = 0; nj < 2; ++nj) {
      const int col = n0 + wave_n * 32 + nj * 16 + fr;
      const float bv = bias[col];
#pragma unroll
      for (int rr = 0; rr < 4; ++rr) {
        const int row = m0 + wave_m * 128 + mi * 16 + fq * 4 + rr;
        Cout[(size_t)row * Nn + col] = acc[mi][nj][rr] + bv + resid[(size_t)row * Nn + col];
      }
    }
  }
}

// ---------------------------------------------------------------- edge pass (bucket CSR + edge records)
// 4-stage pipeline: bucket@i+4, rec@i+3, kv@i+2, compute@i.
// Dot product: 4 parallel 4-deep fmaf chains + tree combine.
__global__ __launch_bounds__(256) void edge_csr(
    const unsigned char* __restrict__ qk8, const float* __restrict__ rec,
    const int* __restrict__ cntp, const int* __restrict__ bucket,
    const float* __restrict__ pos, u16* __restrict__ zcat)
{
  const int lane = threadIdx.x & 63;
  const int wave = threadIdx.x >> 6;
  const int row = blockIdx.x * 4 + wave;
  const int half = lane >> 5;
  const int sub = lane & 31;
  const int h = sub >> 2, j = sub & 3;
  const int deg = min(cntp[row * 16], 64);
  const int base = row * 64;

  const uint4 qv = *(const uint4*)(qk8 + (size_t)row * 1024 + sub * 16);
  float qf[16];
  {
    const unsigned int* qu = (const unsigned int*)&qv;
#pragma unroll
    for (int i = 0; i < 4; ++i) {
      const f32x2 lo = __builtin_amdgcn_cvt_pk_f32_fp8(qu[i], false);
      const f32x2 hi = __builtin_amdgcn_cvt_pk_f32_fp8(qu[i], true);
      qf[i * 4 + 0] = lo.x; qf[i * 4 + 1] = lo.y;
      qf[i * 4 + 2] = hi.x; qf[i * 4 + 3] = hi.y;
    }
  }

  float accA = 0.f, accB = 0.f;
  const int npair = (deg + 1) >> 1;

  bool ok0 = half < deg;
  int e0 = ok0 ? bucket[base + half] : 0;
  const float* r0 = rec + (size_t)e0 * 16;
  float bias0 = r0[h], invd0 = r0[8];
  float spA0 = (j >= 2) ? r0[7 + j] : 0.f;
  float spB0 = (j == 1) ? r0[11] : 0.f;
  uint4 kv0 = *(const uint4*)(qk8 + (size_t)__float_as_int(r0[12]) * 1024 + 512 + sub * 16);

  bool ok1 = 2 + half < deg;
  int e1 = ok1 ? bucket[base + 2 + half] : 0;
  const float* r1 = rec + (size_t)e1 * 16;
  float bias1 = r1[h], invd1 = r1[8];
  float spA1 = (j >= 2) ? r1[7 + j] : 0.f;
  float spB1 = (j == 1) ? r1[11] : 0.f;
  uint4 kv1 = *(const uint4*)(qk8 + (size_t)__float_as_int(r1[12]) * 1024 + 512 + sub * 16);

  bool ok2 = 4 + half < deg;
  int e2 = ok2 ? bucket[base + 4 + half] : 0;
  const float* r2p = rec + (size_t)e2 * 16;
  float bias2 = r2p[h], invd2 = r2p[8];
  float spA2 = (j >= 2) ? r2p[7 + j] : 0.f;
  float spB2 = (j == 1) ? r2p[11] : 0.f;
  int kr2 = __float_as_int(r2p[12]);

  bool ok3 = 6 + half < deg;
  int e3 = ok3 ? bucket[base + 6 + half] : 0;

  for (int i = 0; i < npair; ++i) {
    const uint4 kv2 = *(const uint4*)(qk8 + (size_t)kr2 * 1024 + 512 + sub * 16);
    const float* r3 = rec + (size_t)e3 * 16;
    const float bias3 = r3[h], invd3 = r3[8];
    const float spA3 = (j >= 2) ? r3[7 + j] : 0.f;
    const float spB3 = (j == 1) ? r3[11] : 0.f;
    const int kr3 = __float_as_int(r3[12]);
    const bool ok4 = 2 * (i + 4) + half < deg;
    const int e4 = ok4 ? bucket[base + 2 * (i + 4) + half] : 0;

    float p;
    {
      const unsigned int* ku = (const unsigned int*)&kv0;
      const f32x2 a0 = __builtin_amdgcn_cvt_pk_f32_fp8(ku[0], false);
      const f32x2 a1 = __builtin_amdgcn_cvt_pk_f32_fp8(ku[0], true);
      const f32x2 b0 = __builtin_amdgcn_cvt_pk_f32_fp8(ku[1], false);
      const f32x2 b1 = __builtin_amdgcn_cvt_pk_f32_fp8(ku[1], true);
      const f32x2 c0 = __builtin_amdgcn_cvt_pk_f32_fp8(ku[2], false);
      const f32x2 c1 = __builtin_amdgcn_cvt_pk_f32_fp8(ku[2], true);
      const f32x2 d0 = __builtin_amdgcn_cvt_pk_f32_fp8(ku[3], false);
      const f32x2 d1 = __builtin_amdgcn_cvt_pk_f32_fp8(ku[3], true);
      float pA = qf[0] * a0.x;
      float pB = qf[4] * b0.x;
      float pC = qf[8] * c0.x;
      float pD = qf[12] * d0.x;
      pA = fmaf(qf[1],  a0.y, pA);  pB = fmaf(qf[5],  b0.y, pB);
      pC = fmaf(qf[9],  c0.y, pC);  pD = fmaf(qf[13], d0.y, pD);
      pA = fmaf(qf[2],  a1.x, pA);  pB = fmaf(qf[6],  b1.x, pB);
      pC = fmaf(qf[10], c1.x, pC);  pD = fmaf(qf[14], d1.x, pD);
      pA = fmaf(qf[3],  a1.y, pA);  pB = fmaf(qf[7],  b1.y, pB);
      pC = fmaf(qf[11], c1.y, pC);  pD = fmaf(qf[15], d1.y, pD);
      p = (pA + pB) + (pC + pD);
    }
    p += __shfl_xor(p, 1, 64);
    p += __shfl_xor(p, 2, 64);
    float pe = __expf(p * 0.125f + bias0);
    pe = ok0 ? pe : 0.f;
    const float w = pe * invd0;
    accA += (j == 0) ? pe : (j == 1) ? w : w * spA0;
    accB += w * spB0;

    ok0 = ok1; bias0 = bias1; invd0 = invd1; spA0 = spA1; spB0 = spB1; kv0 = kv1;
    ok1 = ok2; bias1 = bias2; invd1 = invd2; spA1 = spA2; spB1 = spB2; kv1 = kv2;
    ok2 = ok3; bias2 = bias3; invd2 = invd3; spA2 = spA3; spB2 = spB3; kr2 = kr3;
    ok3 = ok4; e3 = e4;
  }

  accA += __shfl_xor(accA, 32, 64);
  accB += __shfl_xor(accB, 32, 64);
  const int hb = h << 2;
  const float den  = __shfl(accA, hb + 0, 64);
  const float wsum = __shfl(accA, hb + 1, 64);
  const float wsp01 = __shfl(accA, hb + 2 + (j & 1), 64);
  const float wsp2  = __shfl(accB, hb + 1, 64);
  const float invd = (den != 0.f) ? 1.f / den : 0.f;
  const float rsum = wsum * invd;
  if (half == 0 && j < 3) {
    const float wspj = (j < 2) ? wsp01 : wsp2;
    zcat[(size_t)row * KIN + D + h * 3 + j] = f2bf(wspj * invd - rsum * pos[row * 3 + j]);
  }
}

// ---------------------------------------------------------------- launch
extern "C" void kernel_launch(void* const* d_in, const int* in_sizes, int n_in,
                              void* d_out, int out_size, void* d_ws, size_t ws_size,
                              hipStream_t stream)
{
  const float* x        = (const float*)d_in[0];
  const float* Wq       = (const float*)d_in[1];
  const float* bq       = (const float*)d_in[2];
  const float* Wk       = (const float*)d_in[3];
  const float* bk       = (const float*)d_in[4];
  const float* g_att    = (const float*)d_in[5];
  const float* b_att    = (const float*)d_in[6];
  const float* g_mlp    = (const float*)d_in[7];
  const float* b_mlp    = (const float*)d_in[8];
  const float* W_in     = (const float*)d_in[9];
  const float* b_in     = (const float*)d_in[10];
  const float* W_out    = (const float*)d_in[11];
  const float* b_out    = (const float*)d_in[12];
  const float* att_bias = (const float*)d_in[13];
  const float* dist     = (const float*)d_in[14];
  const float* pos      = (const float*)d_in[15];
  const float* src_pos  = (const float*)d_in[16];
  const int* row_index  = (const int*)d_in[17];
  const int* src_index  = (const int*)d_in[18];
  const int* org_to_src = (const int*)d_in[19];

  char* ws = (char*)d_ws;
  u16*   zatt = (u16*)(ws + OFF_ZATT);
  u16*   zcat = (u16*)(ws + OFF_ZCAT);
  u16*   wqk  = (u16*)(ws + OFF_WQK);
  float* bqk  = (float*)(ws + OFF_BQK);
  u16*   win  = (u16*)(ws + OFF_WIN);
  u16*   wout = (u16*)(ws + OFF_WOUT);
  unsigned char* qk8 = (unsigned char*)(ws + OFF_QK);
  int*   bkt  = (int*)(ws + OFF_BKT);
  u16*   hbf  = (u16*)(ws + OFF_HBF);
  float* rec  = (float*)(ws + OFF_REC);
  int*   cntp = (int*)(ws + OFF_CNTP);

  static bool s_attr = false;
  if (!s_attr) {
    hipFuncSetAttribute(reinterpret_cast<const void*>(&gemm256<4>),
                        hipFuncAttributeMaxDynamicSharedMemorySize, 131072);
    hipFuncSetAttribute(reinterpret_cast<const void*>(&gemm256<1>),
                        hipFuncAttributeMaxDynamicSharedMemorySize, 131072);
    hipFuncSetAttribute(reinterpret_cast<const void*>(&gemm_mlp),
                        hipFuncAttributeMaxDynamicSharedMemorySize, 98304);
    s_attr = true;
  }

  hipMemsetAsync(ws + OFF_CNTP, 0, 16384 * 64, stream);

  prep_all<<<1024 + 288 + 4096, 256, 0, stream>>>(
      row_index, att_bias, dist, src_pos, src_index, org_to_src, cntp, bkt, rec,
      Wq, Wk, bq, bk, W_in, W_out, wqk, bqk, win, wout,
      x, g_att, b_att, g_mlp, b_mlp, zatt, zcat);
  gemm256<4><<<dim3(64, 4), 512, 131072, stream>>>(zatt, wqk, bqk, qk8, N_NODES, 1024, 512);
  edge_csr<<<N_NODES / 4, 256, 0, stream>>>(qk8, rec, cntp, bkt, pos, zcat);
  gemm256<1><<<dim3(64, 4), 512, 131072, stream>>>(zcat, win, b_in, hbf, N_NODES, 1024, KIN);
  gemm_mlp<<<dim3(64, 4), 512, 98304, stream>>>(hbf, wout, b_out, x, (float*)d_out, N_NODES, 512, 1024);
}